// Round 4
// baseline (463.955 us; speedup 1.0000x reference)
//
#include <hip/hip_runtime.h>
#include <hip/hip_bf16.h>

typedef unsigned short ushort_t;
typedef __attribute__((ext_vector_type(8))) short short8;
typedef __attribute__((ext_vector_type(4))) float f32x4;
typedef __attribute__((ext_vector_type(4))) unsigned short us4;

#define B_SZ 8192
#define D_FT 784
#define K_PAD 832   // 13 * 64
#define N_KT 13
#define THRESH 0.9f

#define GLOBAL_AS(p) ((const __attribute__((address_space(1))) void*)(p))
#define LDS_AS(p)    ((__attribute__((address_space(3))) void*)(p))

__device__ inline unsigned short f2bf(float f) {
    unsigned int u = __float_as_uint(f);
    unsigned int r = (u + 0x7fffu + ((u >> 16) & 1u)) >> 16;
    return (unsigned short)r;
}

// Wave-per-row preproc: 2048 blocks x 4 waves; wave w handles row blockIdx*4+w.
__global__ __launch_bounds__(256) void preproc_kernel(
    const float* __restrict__ x, const float* __restrict__ conv_w,
    const float* __restrict__ conv_b, const float* __restrict__ unitary,
    const float* __restrict__ lin_w, const float* __restrict__ lin_b,
    float* __restrict__ log_probs, ushort_t* __restrict__ qn)
{
    __shared__ float xr[4][784];
    __shared__ float qf[4][784];

    const int t = threadIdx.x, lane = t & 63, wave = t >> 6;
    const int b = blockIdx.x * 4 + wave;
    float* xw = xr[wave];
    float* qw = qf[wave];

    const float4* xsrc = (const float4*)(x + (size_t)b * 784);
    #pragma unroll
    for (int i = lane; i < 196; i += 64) ((float4*)xw)[i] = xsrc[i];
    __syncthreads();

    float sumsq = 0.f;
    for (int g = lane; g < 196; g += 64) {
        const int c = g / 49, p = g % 49;
        const float w00 = conv_w[c*4+0], w01 = conv_w[c*4+1];
        const float w10 = conv_w[c*4+2], w11 = conv_w[c*4+3];
        const float bcv = conv_b[c];
        float feat[4];
        #pragma unroll
        for (int j = 0; j < 4; ++j) {
            const int s = 4*p + j;
            const int h = s / 14, wq = s % 14;
            const float* px = &xw[(2*h)*28 + 2*wq];
            feat[j] = bcv + w00*px[0] + w01*px[1] + w10*px[28] + w11*px[29];
        }
        #pragma unroll
        for (int w = 0; w < 4; ++w) {
            float v = unitary[w*4+0]*feat[0] + unitary[w*4+1]*feat[1]
                    + unitary[w*4+2]*feat[2] + unitary[w*4+3]*feat[3];
            qw[4*g + w] = v;
            sumsq += v * v;
        }
    }
    __syncthreads();

    #pragma unroll
    for (int off = 1; off < 64; off <<= 1) sumsq += __shfl_xor(sumsq, off, 64);
    const float inv = 1.0f / (sqrtf(sumsq) + 1e-12f);

    ushort_t* qrow = qn + (size_t)b * K_PAD;
    for (int i = lane; i < 208; i += 64) {
        us4 o;
        if (i < 196) {
            #pragma unroll
            for (int j = 0; j < 4; ++j) o[j] = f2bf(qw[4*i + j] * inv);
        } else {
            o = (us4)0;
        }
        *(us4*)(qrow + 4*i) = o;
    }

    float acc[10];
    #pragma unroll
    for (int cl = 0; cl < 10; ++cl) acc[cl] = 0.f;
    for (int k = lane; k < 784; k += 64) {
        const float v = qw[k];
        #pragma unroll
        for (int cl = 0; cl < 10; ++cl) acc[cl] += v * lin_w[cl*784 + k];
    }
    #pragma unroll
    for (int cl = 0; cl < 10; ++cl) {
        #pragma unroll
        for (int off = 1; off < 64; off <<= 1)
            acc[cl] += __shfl_xor(acc[cl], off, 64);
        acc[cl] += lin_b[cl];
    }
    if (lane == 0) {
        float mx = -1e30f;
        #pragma unroll
        for (int cl = 0; cl < 10; ++cl) mx = fmaxf(mx, acc[cl]);
        float se = 0.f;
        #pragma unroll
        for (int cl = 0; cl < 10; ++cl) se += expf(acc[cl] - mx);
        const float lse = mx + logf(se);
        #pragma unroll
        for (int cl = 0; cl < 10; ++cl)
            log_probs[(size_t)b*10 + cl] = acc[cl] - lse;
    }
}

// Symmetric 128x128-tile Gram GEMM, 2 waves/block, wave-tile 64x128 (4x8 accs).
// Per s-step: 12 ds_read_b128 feed 32 MFMA -> MFMA-bound (was 8:16 LDS-bound).
// BK=64, conflict-free sub-chunk-major LDS layout:
//   per 16-row block rb (1024 ushorts): [ksub 0..7][row 0..15][8 elems]
//   global_load_lds lane map: row = lane&15, ksub = L*4 + (lane>>4).
__global__ __launch_bounds__(128, 2) void gram_kernel(
    const ushort_t* __restrict__ qn, float* __restrict__ adj)
{
    const int br = blockIdx.y, bc = blockIdx.x;
    if (br > bc) return;   // symmetry: upper-triangular block pairs only

    __shared__ ushort_t ldsA[128*64] __attribute__((aligned(16)));  // 16 KB
    __shared__ ushort_t ldsB[128*64] __attribute__((aligned(16)));  // 16 KB

    const int t = threadIdx.x;
    const int lane = t & 63, wave = t >> 6;        // wave 0..1
    const int quad = lane >> 4, l16 = lane & 15;

    const int rowA0 = br * 128, rowB0 = bc * 128;

    // staging: wave w stages row-blocks 4w..4w+3 of both A and B
    const int row_in = lane & 15;
    const int ksub4  = lane >> 4;   // 0..3
    const ushort_t* gA = qn + (size_t)(rowA0 + wave*64 + row_in) * K_PAD + ksub4*8;
    const ushort_t* gB = qn + (size_t)(rowB0 + wave*64 + row_in) * K_PAD + ksub4*8;
    ushort_t* lA = &ldsA[wave * 4 * 1024];
    ushort_t* lB = &ldsB[wave * 4 * 1024];

    f32x4 acc[4][8] = {};

    for (int kt = 0; kt < N_KT; ++kt) {
        const ushort_t* ga = gA + kt * 64;
        const ushort_t* gb = gB + kt * 64;
        #pragma unroll
        for (int mi = 0; mi < 4; ++mi) {
            #pragma unroll
            for (int L = 0; L < 2; ++L) {
                __builtin_amdgcn_global_load_lds(
                    GLOBAL_AS(ga + mi*16*K_PAD + L*32),
                    LDS_AS(lA + mi*1024 + L*512), 16, 0, 0);
                __builtin_amdgcn_global_load_lds(
                    GLOBAL_AS(gb + mi*16*K_PAD + L*32),
                    LDS_AS(lB + mi*1024 + L*512), 16, 0, 0);
            }
        }
        __syncthreads();

        #pragma unroll
        for (int s = 0; s < 2; ++s) {
            short8 af[4], bf[8];
            #pragma unroll
            for (int mi = 0; mi < 4; ++mi)
                af[mi] = *(const short8*)&ldsA[(wave*4 + mi)*1024 + (s*4 + quad)*128 + l16*8];
            #pragma unroll
            for (int ni = 0; ni < 8; ++ni)
                bf[ni] = *(const short8*)&ldsB[ni*1024 + (s*4 + quad)*128 + l16*8];
            #pragma unroll
            for (int mi = 0; mi < 4; ++mi)
                #pragma unroll
                for (int ni = 0; ni < 8; ++ni)
                    acc[mi][ni] = __builtin_amdgcn_mfma_f32_16x16x32_bf16(
                        af[mi], bf[ni], acc[mi][ni], 0, 0, 0);
        }
        __syncthreads();
    }

    // epilogue: fid = c^2, threshold, zero diagonal; off-diag tiles also
    // store the transpose (float4 over 4 consecutive acc rows).
    const bool offdiag = (br != bc);
    #pragma unroll
    for (int mi = 0; mi < 4; ++mi) {
        const int gr0 = br*128 + wave*64 + mi*16 + quad*4;
        #pragma unroll
        for (int ni = 0; ni < 8; ++ni) {
            const int gc = bc*128 + ni*16 + l16;
            const f32x4 v = acc[mi][ni];
            float o[4];
            #pragma unroll
            for (int r = 0; r < 4; ++r)
                o[r] = (v[r]*v[r] >= THRESH && (gr0 + r) != gc) ? 1.0f : 0.0f;
            #pragma unroll
            for (int r = 0; r < 4; ++r)
                adj[(size_t)(gr0 + r) * B_SZ + gc] = o[r];
            if (offdiag)
                *(float4*)&adj[(size_t)gc * B_SZ + gr0] =
                    make_float4(o[0], o[1], o[2], o[3]);
        }
    }
}

extern "C" void kernel_launch(void* const* d_in, const int* in_sizes, int n_in,
                              void* d_out, int out_size, void* d_ws, size_t ws_size,
                              hipStream_t stream) {
    const float* x       = (const float*)d_in[0];
    const float* conv_w  = (const float*)d_in[1];
    const float* conv_b  = (const float*)d_in[2];
    const float* unitary = (const float*)d_in[3];
    const float* lin_w   = (const float*)d_in[4];
    const float* lin_b   = (const float*)d_in[5];

    float* log_probs = (float*)d_out;
    float* adj       = (float*)d_out + (size_t)B_SZ * 10;
    ushort_t* qn     = (ushort_t*)d_ws;   // [8192, 832] bf16

    preproc_kernel<<<B_SZ / 4, 256, 0, stream>>>(x, conv_w, conv_b, unitary,
                                                 lin_w, lin_b, log_probs, qn);
    gram_kernel<<<dim3(64, 64), 128, 0, stream>>>(qn, adj);
}

// Round 5
// 428.581 us; speedup vs baseline: 1.0825x; 1.0825x over previous
//
#include <hip/hip_runtime.h>
#include <hip/hip_bf16.h>

typedef unsigned short ushort_t;
typedef __attribute__((ext_vector_type(8))) short short8;
typedef __attribute__((ext_vector_type(4))) float f32x4;
typedef __attribute__((ext_vector_type(4))) unsigned short us4;

#define B_SZ 8192
#define D_FT 784
#define K_PAD 800   // 25 * 32
#define N_KT 25
#define THRESH 0.9f

#define GLOBAL_AS(p) ((const __attribute__((address_space(1))) void*)(p))
#define LDS_AS(p)    ((__attribute__((address_space(3))) void*)(p))

__device__ inline unsigned short f2bf(float f) {
    unsigned int u = __float_as_uint(f);
    unsigned int r = (u + 0x7fffu + ((u >> 16) & 1u)) >> 16;
    return (unsigned short)r;
}

// Wave-per-row preproc: 2048 blocks x 4 waves; wave w handles row blockIdx*4+w.
__global__ __launch_bounds__(256) void preproc_kernel(
    const float* __restrict__ x, const float* __restrict__ conv_w,
    const float* __restrict__ conv_b, const float* __restrict__ unitary,
    const float* __restrict__ lin_w, const float* __restrict__ lin_b,
    float* __restrict__ log_probs, ushort_t* __restrict__ qn)
{
    __shared__ float xr[4][784];
    __shared__ float qf[4][784];

    const int t = threadIdx.x, lane = t & 63, wave = t >> 6;
    const int b = blockIdx.x * 4 + wave;
    float* xw = xr[wave];
    float* qw = qf[wave];

    const float4* xsrc = (const float4*)(x + (size_t)b * 784);
    #pragma unroll
    for (int i = lane; i < 196; i += 64) ((float4*)xw)[i] = xsrc[i];
    __syncthreads();

    float sumsq = 0.f;
    for (int g = lane; g < 196; g += 64) {
        const int c = g / 49, p = g % 49;
        const float w00 = conv_w[c*4+0], w01 = conv_w[c*4+1];
        const float w10 = conv_w[c*4+2], w11 = conv_w[c*4+3];
        const float bcv = conv_b[c];
        float feat[4];
        #pragma unroll
        for (int j = 0; j < 4; ++j) {
            const int s = 4*p + j;
            const int h = s / 14, wq = s % 14;
            const float* px = &xw[(2*h)*28 + 2*wq];
            feat[j] = bcv + w00*px[0] + w01*px[1] + w10*px[28] + w11*px[29];
        }
        #pragma unroll
        for (int w = 0; w < 4; ++w) {
            float v = unitary[w*4+0]*feat[0] + unitary[w*4+1]*feat[1]
                    + unitary[w*4+2]*feat[2] + unitary[w*4+3]*feat[3];
            qw[4*g + w] = v;
            sumsq += v * v;
        }
    }
    __syncthreads();

    #pragma unroll
    for (int off = 1; off < 64; off <<= 1) sumsq += __shfl_xor(sumsq, off, 64);
    const float inv = 1.0f / (sqrtf(sumsq) + 1e-12f);

    ushort_t* qrow = qn + (size_t)b * K_PAD;
    for (int i = lane; i < 200; i += 64) {
        us4 o;
        if (i < 196) {
            #pragma unroll
            for (int j = 0; j < 4; ++j) o[j] = f2bf(qw[4*i + j] * inv);
        } else {
            o = (us4)0;
        }
        *(us4*)(qrow + 4*i) = o;
    }

    float acc[10];
    #pragma unroll
    for (int cl = 0; cl < 10; ++cl) acc[cl] = 0.f;
    for (int k = lane; k < 784; k += 64) {
        const float v = qw[k];
        #pragma unroll
        for (int cl = 0; cl < 10; ++cl) acc[cl] += v * lin_w[cl*784 + k];
    }
    #pragma unroll
    for (int cl = 0; cl < 10; ++cl) {
        #pragma unroll
        for (int off = 1; off < 64; off <<= 1)
            acc[cl] += __shfl_xor(acc[cl], off, 64);
        acc[cl] += lin_b[cl];
    }
    if (lane == 0) {
        float mx = -1e30f;
        #pragma unroll
        for (int cl = 0; cl < 10; ++cl) mx = fmaxf(mx, acc[cl]);
        float se = 0.f;
        #pragma unroll
        for (int cl = 0; cl < 10; ++cl) se += expf(acc[cl] - mx);
        const float lse = mx + logf(se);
        #pragma unroll
        for (int cl = 0; cl < 10; ++cl)
            log_probs[(size_t)b*10 + cl] = acc[cl] - lse;
    }
}

// Symmetric 128x128-tile Gram GEMM, BK=32, 4 waves (64x64 wave-tiles),
// conflict-free sub-chunk LDS layout, explicit LDS double-buffer with raw
// s_barrier + fine-grained vmcnt(4) so prefetch glds stay in flight across
// the barrier (the __syncthreads vmcnt(0) drain was the latency bottleneck).
// Per 16-row block rb (512 ushorts): [ksub 0..3][row 0..15][8 elems];
// glds lane map row=lane&15, ksub=lane>>4 matches it exactly.
__global__ __launch_bounds__(256, 4) void gram_kernel(
    const ushort_t* __restrict__ qn, float* __restrict__ adj)
{
    const int br = blockIdx.y, bc = blockIdx.x;
    if (br > bc) return;   // symmetry: upper-triangular block pairs only

    __shared__ ushort_t ldsA[2][4096] __attribute__((aligned(16)));  // 2x8KB
    __shared__ ushort_t ldsB[2][4096] __attribute__((aligned(16)));  // 2x8KB

    const int t = threadIdx.x;
    const int lane = t & 63, wave = t >> 6;
    const int wr = wave >> 1, wc = wave & 1;
    const int quad = lane >> 4, l16 = lane & 15;

    // staging: wave w stages row-blocks {w, w+4} of A and B (4 glds/kt)
    const int srow = lane & 15, sk = (lane >> 4) * 8;
    const ushort_t* gA0 = qn + (size_t)(br*128 + wave*16     + srow) * K_PAD + sk;
    const ushort_t* gA1 = qn + (size_t)(br*128 + (wave+4)*16 + srow) * K_PAD + sk;
    const ushort_t* gB0 = qn + (size_t)(bc*128 + wave*16     + srow) * K_PAD + sk;
    const ushort_t* gB1 = qn + (size_t)(bc*128 + (wave+4)*16 + srow) * K_PAD + sk;
    const int ld0 = wave * 512, ld1 = (wave + 4) * 512;

    #define STAGE(p, koff) do {                                                            \
        __builtin_amdgcn_global_load_lds(GLOBAL_AS(gA0 + (koff)), LDS_AS(&ldsA[p][ld0]), 16, 0, 0); \
        __builtin_amdgcn_global_load_lds(GLOBAL_AS(gA1 + (koff)), LDS_AS(&ldsA[p][ld1]), 16, 0, 0); \
        __builtin_amdgcn_global_load_lds(GLOBAL_AS(gB0 + (koff)), LDS_AS(&ldsB[p][ld0]), 16, 0, 0); \
        __builtin_amdgcn_global_load_lds(GLOBAL_AS(gB1 + (koff)), LDS_AS(&ldsB[p][ld1]), 16, 0, 0); \
    } while (0)

    f32x4 acc[4][4] = {};
    STAGE(0, 0);

    for (int kt = 0; kt < N_KT; ++kt) {
        const int p = kt & 1;
        if (kt + 1 < N_KT) {
            STAGE(p ^ 1, (kt + 1) * 32);                  // prefetch next tile
            asm volatile("" ::: "memory");
            __builtin_amdgcn_s_waitcnt(0xF74);            // vmcnt(4): cur tile done
        } else {
            asm volatile("" ::: "memory");
            __builtin_amdgcn_s_waitcnt(0xF70);            // vmcnt(0)
        }
        __builtin_amdgcn_s_barrier();
        asm volatile("" ::: "memory");

        short8 bfr[4];
        #pragma unroll
        for (int ni = 0; ni < 4; ++ni)
            bfr[ni] = *(const short8*)&ldsB[p][(wc*4 + ni)*512 + quad*128 + l16*8];
        #pragma unroll
        for (int mi = 0; mi < 4; ++mi) {
            const short8 af = *(const short8*)&ldsA[p][(wr*4 + mi)*512 + quad*128 + l16*8];
            #pragma unroll
            for (int ni = 0; ni < 4; ++ni)
                acc[mi][ni] = __builtin_amdgcn_mfma_f32_16x16x32_bf16(
                    af, bfr[ni], acc[mi][ni], 0, 0, 0);
        }

        asm volatile("" ::: "memory");
        __builtin_amdgcn_s_barrier();                     // reads done before overwrite
        asm volatile("" ::: "memory");
    }
    #undef STAGE

    // epilogue: fid = c^2, threshold, zero diagonal; off-diag tiles also
    // store the transpose (float4 over 4 consecutive acc rows = one 64B
    // line per 4 quad-lanes -> full-line dirtying both directions).
    const bool offdiag = (br != bc);
    #pragma unroll
    for (int mi = 0; mi < 4; ++mi) {
        const int gr0 = br*128 + wr*64 + mi*16 + quad*4;
        #pragma unroll
        for (int ni = 0; ni < 4; ++ni) {
            const int gc = bc*128 + wc*64 + ni*16 + l16;
            const f32x4 v = acc[mi][ni];
            float o[4];
            #pragma unroll
            for (int r = 0; r < 4; ++r)
                o[r] = (v[r]*v[r] >= THRESH && (gr0 + r) != gc) ? 1.0f : 0.0f;
            #pragma unroll
            for (int r = 0; r < 4; ++r)
                adj[(size_t)(gr0 + r) * B_SZ + gc] = o[r];
            if (offdiag)
                *(float4*)&adj[(size_t)gc * B_SZ + gr0] =
                    make_float4(o[0], o[1], o[2], o[3]);
        }
    }
}

extern "C" void kernel_launch(void* const* d_in, const int* in_sizes, int n_in,
                              void* d_out, int out_size, void* d_ws, size_t ws_size,
                              hipStream_t stream) {
    const float* x       = (const float*)d_in[0];
    const float* conv_w  = (const float*)d_in[1];
    const float* conv_b  = (const float*)d_in[2];
    const float* unitary = (const float*)d_in[3];
    const float* lin_w   = (const float*)d_in[4];
    const float* lin_b   = (const float*)d_in[5];

    float* log_probs = (float*)d_out;
    float* adj       = (float*)d_out + (size_t)B_SZ * 10;
    ushort_t* qn     = (ushort_t*)d_ws;   // [8192, 800] bf16

    preproc_kernel<<<B_SZ / 4, 256, 0, stream>>>(x, conv_w, conv_b, unitary,
                                                 lin_w, lin_b, log_probs, qn);
    gram_kernel<<<dim3(64, 64), 256, 0, stream>>>(qn, adj);
}

// Round 6
// 383.605 us; speedup vs baseline: 1.2095x; 1.1172x over previous
//
#include <hip/hip_runtime.h>
#include <hip/hip_bf16.h>

typedef unsigned char uchar_t;
typedef __attribute__((ext_vector_type(4))) float f32x4;

#define B_SZ 8192
#define D_FT 784
#define K_PAD 832   // 13 * 64 fp8 bytes per row
#define N_KT 13
#define THRESH 0.9f

#define GLOBAL_AS(p) ((const __attribute__((address_space(1))) void*)(p))
#define LDS_AS(p)    ((__attribute__((address_space(3))) void*)(p))

// Wave-per-row preproc: 2048 blocks x 4 waves; wave w handles row blockIdx*4+w.
// conv 2x2/s2 + bias -> 4x4 unitary -> qf (LDS, fp32), row norm -> qn fp8 e4m3
// (packed via v_cvt_pk_fp8_f32, padded to 832), logits + log_softmax (fp32).
__global__ __launch_bounds__(256) void preproc_kernel(
    const float* __restrict__ x, const float* __restrict__ conv_w,
    const float* __restrict__ conv_b, const float* __restrict__ unitary,
    const float* __restrict__ lin_w, const float* __restrict__ lin_b,
    float* __restrict__ log_probs, uchar_t* __restrict__ qn)
{
    __shared__ float xr[4][784];
    __shared__ float qf[4][784];

    const int t = threadIdx.x, lane = t & 63, wave = t >> 6;
    const int b = blockIdx.x * 4 + wave;
    float* xw = xr[wave];
    float* qw = qf[wave];

    const float4* xsrc = (const float4*)(x + (size_t)b * 784);
    #pragma unroll
    for (int i = lane; i < 196; i += 64) ((float4*)xw)[i] = xsrc[i];
    __syncthreads();

    float sumsq = 0.f;
    for (int g = lane; g < 196; g += 64) {
        const int c = g / 49, p = g % 49;
        const float w00 = conv_w[c*4+0], w01 = conv_w[c*4+1];
        const float w10 = conv_w[c*4+2], w11 = conv_w[c*4+3];
        const float bcv = conv_b[c];
        float feat[4];
        #pragma unroll
        for (int j = 0; j < 4; ++j) {
            const int s = 4*p + j;
            const int h = s / 14, wq = s % 14;
            const float* px = &xw[(2*h)*28 + 2*wq];
            feat[j] = bcv + w00*px[0] + w01*px[1] + w10*px[28] + w11*px[29];
        }
        #pragma unroll
        for (int w = 0; w < 4; ++w) {
            float v = unitary[w*4+0]*feat[0] + unitary[w*4+1]*feat[1]
                    + unitary[w*4+2]*feat[2] + unitary[w*4+3]*feat[3];
            qw[4*g + w] = v;
            sumsq += v * v;
        }
    }
    __syncthreads();

    #pragma unroll
    for (int off = 1; off < 64; off <<= 1) sumsq += __shfl_xor(sumsq, off, 64);
    const float inv = 1.0f / (sqrtf(sumsq) + 1e-12f);

    // qn write: 208 uints (4 fp8 each) = 832 B, zero-padded past 784
    unsigned int* qrow = (unsigned int*)(qn + (size_t)b * K_PAD);
    for (int i = lane; i < 208; i += 64) {
        unsigned int o = 0u;
        if (i < 196) {
            const float v0 = qw[4*i+0] * inv, v1 = qw[4*i+1] * inv;
            const float v2 = qw[4*i+2] * inv, v3 = qw[4*i+3] * inv;
            int lo = __builtin_amdgcn_cvt_pk_fp8_f32(v0, v1, 0, 0);
            o = (unsigned int)__builtin_amdgcn_cvt_pk_fp8_f32(v2, v3, lo, 1);
        }
        qrow[i] = o;
    }

    float acc[10];
    #pragma unroll
    for (int cl = 0; cl < 10; ++cl) acc[cl] = 0.f;
    for (int k = lane; k < 784; k += 64) {
        const float v = qw[k];
        #pragma unroll
        for (int cl = 0; cl < 10; ++cl) acc[cl] += v * lin_w[cl*784 + k];
    }
    #pragma unroll
    for (int cl = 0; cl < 10; ++cl) {
        #pragma unroll
        for (int off = 1; off < 64; off <<= 1)
            acc[cl] += __shfl_xor(acc[cl], off, 64);
        acc[cl] += lin_b[cl];
    }
    if (lane == 0) {
        float mx = -1e30f;
        #pragma unroll
        for (int cl = 0; cl < 10; ++cl) mx = fmaxf(mx, acc[cl]);
        float se = 0.f;
        #pragma unroll
        for (int cl = 0; cl < 10; ++cl) se += expf(acc[cl] - mx);
        const float lse = mx + logf(se);
        #pragma unroll
        for (int cl = 0; cl < 10; ++cl)
            log_probs[(size_t)b*10 + cl] = acc[cl] - lse;
    }
}

// Symmetric 128x128-tile fp8 Gram GEMM, BK=64 (13 kt), 4 waves (64x64 tiles),
// LDS double-buffer + raw s_barrier + vmcnt(4) (R5 scaffold). LDS layout per
// 16-row block rb (1024 B): [kchunk 0..3][row 0..15][16 B]; glds lane map
// row=lane&15, kchunk=lane>>4 matches exactly. Fragment: ds_read_b64 at
// chunk 2s+(quad>>1), half quad&1 -> structural-min bank load (4/bank).
// Per kt per wave: 4 glds + 16 ds_read_b64 + 32 mfma_16x16x32_fp8_fp8.
__global__ __launch_bounds__(256, 4) void gram_kernel(
    const uchar_t* __restrict__ qn, float* __restrict__ adj)
{
    const int br = blockIdx.y, bc = blockIdx.x;
    if (br > bc) return;   // symmetry: upper-triangular block pairs only

    __shared__ uchar_t ldsA[2][8192] __attribute__((aligned(16)));  // 2x8KB
    __shared__ uchar_t ldsB[2][8192] __attribute__((aligned(16)));  // 2x8KB

    const int t = threadIdx.x;
    const int lane = t & 63, wave = t >> 6;
    const int wr = wave >> 1, wc = wave & 1;
    const int quad = lane >> 4, l16 = lane & 15;

    // staging: wave w stages row-blocks {w, w+4} of A and B (4 glds/kt)
    const int srow = lane & 15, sck = (lane >> 4) * 16;  // byte offset in row
    const uchar_t* gA0 = qn + (size_t)(br*128 + wave*16     + srow) * K_PAD + sck;
    const uchar_t* gA1 = qn + (size_t)(br*128 + (wave+4)*16 + srow) * K_PAD + sck;
    const uchar_t* gB0 = qn + (size_t)(bc*128 + wave*16     + srow) * K_PAD + sck;
    const uchar_t* gB1 = qn + (size_t)(bc*128 + (wave+4)*16 + srow) * K_PAD + sck;
    const int ld0 = wave * 1024, ld1 = (wave + 4) * 1024;

    #define STAGE(p, koff) do {                                                            \
        __builtin_amdgcn_global_load_lds(GLOBAL_AS(gA0 + (koff)), LDS_AS(&ldsA[p][ld0]), 16, 0, 0); \
        __builtin_amdgcn_global_load_lds(GLOBAL_AS(gA1 + (koff)), LDS_AS(&ldsA[p][ld1]), 16, 0, 0); \
        __builtin_amdgcn_global_load_lds(GLOBAL_AS(gB0 + (koff)), LDS_AS(&ldsB[p][ld0]), 16, 0, 0); \
        __builtin_amdgcn_global_load_lds(GLOBAL_AS(gB1 + (koff)), LDS_AS(&ldsB[p][ld1]), 16, 0, 0); \
    } while (0)

    f32x4 acc[4][4] = {};
    STAGE(0, 0);

    for (int kt = 0; kt < N_KT; ++kt) {
        const int p = kt & 1;
        if (kt + 1 < N_KT) {
            STAGE(p ^ 1, (kt + 1) * 64);                  // prefetch next tile
            asm volatile("" ::: "memory");
            __builtin_amdgcn_s_waitcnt(0xF74);            // vmcnt(4): cur tile done
        } else {
            asm volatile("" ::: "memory");
            __builtin_amdgcn_s_waitcnt(0xF70);            // vmcnt(0)
        }
        __builtin_amdgcn_s_barrier();
        asm volatile("" ::: "memory");

        #pragma unroll
        for (int s = 0; s < 2; ++s) {
            const int fo = (2*s + (quad >> 1))*256 + l16*16 + (quad & 1)*8;
            long bfr[4];
            #pragma unroll
            for (int ni = 0; ni < 4; ++ni)
                bfr[ni] = *(const long*)&ldsB[p][(wc*4 + ni)*1024 + fo];
            #pragma unroll
            for (int mi = 0; mi < 4; ++mi) {
                const long af = *(const long*)&ldsA[p][(wr*4 + mi)*1024 + fo];
                #pragma unroll
                for (int ni = 0; ni < 4; ++ni)
                    acc[mi][ni] = __builtin_amdgcn_mfma_f32_16x16x32_fp8_fp8(
                        af, bfr[ni], acc[mi][ni], 0, 0, 0);
            }
        }

        asm volatile("" ::: "memory");
        __builtin_amdgcn_s_barrier();                     // reads done before overwrite
        asm volatile("" ::: "memory");
    }
    #undef STAGE

    // epilogue: fid = c^2, threshold, zero diagonal; off-diag tiles also
    // store the transpose (float4 over 4 consecutive acc rows).
    const bool offdiag = (br != bc);
    #pragma unroll
    for (int mi = 0; mi < 4; ++mi) {
        const int gr0 = br*128 + wr*64 + mi*16 + quad*4;
        #pragma unroll
        for (int ni = 0; ni < 4; ++ni) {
            const int gc = bc*128 + wc*64 + ni*16 + l16;
            const f32x4 v = acc[mi][ni];
            float o[4];
            #pragma unroll
            for (int r = 0; r < 4; ++r)
                o[r] = (v[r]*v[r] >= THRESH && (gr0 + r) != gc) ? 1.0f : 0.0f;
            #pragma unroll
            for (int r = 0; r < 4; ++r)
                adj[(size_t)(gr0 + r) * B_SZ + gc] = o[r];
            if (offdiag)
                *(float4*)&adj[(size_t)gc * B_SZ + gr0] =
                    make_float4(o[0], o[1], o[2], o[3]);
        }
    }
}

extern "C" void kernel_launch(void* const* d_in, const int* in_sizes, int n_in,
                              void* d_out, int out_size, void* d_ws, size_t ws_size,
                              hipStream_t stream) {
    const float* x       = (const float*)d_in[0];
    const float* conv_w  = (const float*)d_in[1];
    const float* conv_b  = (const float*)d_in[2];
    const float* unitary = (const float*)d_in[3];
    const float* lin_w   = (const float*)d_in[4];
    const float* lin_b   = (const float*)d_in[5];

    float* log_probs = (float*)d_out;
    float* adj       = (float*)d_out + (size_t)B_SZ * 10;
    uchar_t* qn      = (uchar_t*)d_ws;   // [8192, 832] fp8 e4m3

    preproc_kernel<<<B_SZ / 4, 256, 0, stream>>>(x, conv_w, conv_b, unitary,
                                                 lin_w, lin_b, log_probs, qn);
    gram_kernel<<<dim3(64, 64), 256, 0, stream>>>(qn, adj);
}